// Round 5
// baseline (357.202 us; speedup 1.0000x reference)
//
#include <hip/hip_runtime.h>
#include <hip/hip_bf16.h>

#define N_ROWS 65536
#define DIMS 256
#define NCLS 64

// ---- ws float-index layout (~16.2 MiB) ----
#define PART_SUM 0        // [1024][64][64] slabs: ((side*4+dq)*128+chunk)
#define BPACK    0        // overlaid on PART_SUM (dead after reduce_kernel)
#define PART_CNT 4194304  // [256][64]  (side*128+chunk)
#define F_SUM_S  4210688  // [64][256]
#define F_SUM_T  4227072  // [64][256]
#define F_CNT    4243456  // [2][64]
#define ACC_OFF  4243584  // 64 doubles (8B aligned)

typedef __attribute__((ext_vector_type(8))) short bf16x8;
typedef __attribute__((ext_vector_type(4))) float f32x4;

__device__ __forceinline__ short f2bf(float f) {
  unsigned u = __float_as_uint(f);
  u += 0x7fffu + ((u >> 16) & 1u);  // RNE
  return (short)(u >> 16);
}
__device__ __forceinline__ unsigned pk2(float x, float y) {
  union { __hip_bfloat162 h; unsigned u; } cv;
  cv.h = __float22bfloat162_rn(make_float2(x, y));  // v_cvt_pk_bf16_f32
  return cv.u;
}
__device__ __forceinline__ bf16x8 pack8(float4 lo, float4 hi) {
  union { unsigned u[4]; bf16x8 v; } cv;
  cv.u[0] = pk2(lo.x, lo.y);
  cv.u[1] = pk2(lo.z, lo.w);
  cv.u[2] = pk2(hi.x, hi.y);
  cv.u[3] = pk2(hi.z, hi.w);
  return cv.v;
}

__device__ __forceinline__ float wave_sum64(float v) {
#pragma unroll
  for (int m = 32; m > 0; m >>= 1) v += __shfl_xor(v, m, 64);
  return v;
}
__device__ __forceinline__ float seg_max16(float v) {
#pragma unroll
  for (int m = 8; m > 0; m >>= 1) v = fmaxf(v, __shfl_xor(v, m, 64));
  return v;
}
__device__ __forceinline__ float seg_sum16(float v) {
#pragma unroll
  for (int m = 8; m > 0; m >>= 1) v += __shfl_xor(v, m, 64);
  return v;
}

// ---------------------------------------------------------------------------
// Kernel 1: segment sums via LDS ds_add_f32 (fire-and-forget, stride-1 banks).
// Grid 1024 = side(2) x dim-quarter(4) x row-chunk(128); 256 thr; 16KB slab.
// 4 blocks/CU -> 16 waves/CU. Each wave: 128 rows, 8-row prefetched batches.
// ---------------------------------------------------------------------------
__global__ __launch_bounds__(256) void seg_sum_kernel(
    const float* __restrict__ src_feat, const float* __restrict__ trg_feat,
    const int* __restrict__ src_label, const int* __restrict__ trg_label,
    float* __restrict__ ws_f) {
  __shared__ float lsum[NCLS * 64];  // 16 KB
  __shared__ float lcnt[NCLS];
  const int tid = threadIdx.x;
  const int wave = tid >> 6;
  const int lane = tid & 63;
  const int b = blockIdx.x;
  const int side = b >> 9;
  const int dq = (b >> 7) & 3;
  const int chunk = b & 127;
  const float* feat = side ? trg_feat : src_feat;
  const int* label = side ? trg_label : src_label;

#pragma unroll
  for (int i = 0; i < 16; ++i) lsum[tid + 256 * i] = 0.f;
  if (tid < NCLS) lcnt[tid] = 0.f;
  __syncthreads();

  const int row0 = chunk * 512 + wave * 128;
  const float* fcol = feat + dq * 64 + lane;
  float cnt = 0.f;

  int lb[8];
  float v[8];
#pragma unroll
  for (int j = 0; j < 8; ++j) {
    lb[j] = label[row0 + j];
    v[j] = fcol[(size_t)(row0 + j) * DIMS];
  }
  for (int it = 0; it < 16; ++it) {
    int nlb[8];
    float nv[8];
    if (it < 15) {
      const int r = row0 + (it + 1) * 8;
#pragma unroll
      for (int j = 0; j < 8; ++j) {
        nlb[j] = label[r + j];
        nv[j] = fcol[(size_t)(r + j) * DIMS];
      }
    }
#pragma unroll
    for (int j = 0; j < 8; ++j) {
      atomicAdd(&lsum[lb[j] * 64 + lane], v[j]);  // ds_add_f32, 2-way alias=free
      if (dq == 0) cnt += (lb[j] == lane) ? 1.f : 0.f;
    }
#pragma unroll
    for (int j = 0; j < 8; ++j) { lb[j] = nlb[j]; v[j] = nv[j]; }
  }
  if (dq == 0) atomicAdd(&lcnt[lane], cnt);
  __syncthreads();

  // flush: contiguous float4 stores, one 16KB slab per block
  float4* ps = (float4*)(ws_f + PART_SUM) + (size_t)b * 1024;
  const float4* l4 = (const float4*)lsum;
#pragma unroll
  for (int k = 0; k < 4; ++k) ps[tid + 256 * k] = l4[tid + 256 * k];
  if (dq == 0 && wave == 0)
    ws_f[PART_CNT + (side * 128 + chunk) * 64 + lane] = lcnt[lane];
}

// ---------------------------------------------------------------------------
// Kernel 2: reduce 128 chunk-partials -> final sums [c][256]; block 256 = cnts.
// ---------------------------------------------------------------------------
__global__ __launch_bounds__(256) void reduce_kernel(float* __restrict__ ws_f) {
  const int tid = threadIdx.x;
  if (blockIdx.x == 256) {
    if (tid < 128) {
      const int side = tid >> 6, c = tid & 63;
      float s = 0.f;
      for (int k = 0; k < 128; ++k)
        s += ws_f[PART_CNT + (side * 128 + k) * 64 + c];
      ws_f[F_CNT + tid] = s;
    }
    return;
  }
  __shared__ float4 red[256];
  const int o = blockIdx.x * 32 + (tid & 31);  // float4 output id 0..8191
  const int side = o >> 12;
  const int rem = o & 4095;
  const int c = rem >> 6;
  const int d4 = rem & 63;
  const int dq = d4 >> 4;
  const int dlow4 = d4 & 15;
  const int kseg = tid >> 5;  // 0..7
  const float4* p = (const float4*)(ws_f + PART_SUM);
  const size_t sbase = ((size_t)(side * 4 + dq) * 128) * 1024 + c * 16 + dlow4;
  float4 s = make_float4(0.f, 0.f, 0.f, 0.f);
  for (int k = kseg * 16; k < kseg * 16 + 16; ++k) {
    const float4 t = p[sbase + (size_t)k * 1024];
    s.x += t.x; s.y += t.y; s.z += t.z; s.w += t.w;
  }
  red[tid] = s;
  __syncthreads();
  if (tid < 32) {
#pragma unroll
    for (int m = 1; m < 8; ++m) {
      const float4 t = red[tid + 32 * m];
      s = red[tid];
      s.x += t.x; s.y += t.y; s.z += t.z; s.w += t.w;
      red[tid] = s;
    }
    ((float4*)(ws_f + (side ? F_SUM_T : F_SUM_S)))[c * 64 + d4] = red[tid];
  }
}

// ---------------------------------------------------------------------------
// Kernel 3: means + B-fragment pack for mfma_f32_16x16x32_bf16.
// B frag: lane l holds u[class = tile*16 + (l&15)][k = s*32 + (l>>4)*8 + j].
// NOTE: BPACK overlays dead PART_SUM (safe: runs after reduce_kernel).
// ---------------------------------------------------------------------------
__global__ __launch_bounds__(64) void pack_kernel(float* __restrict__ ws_f) {
  const int bx = blockIdx.x;  // mat*4 + tile
  const int mat = bx >> 2;
  const int tile = bx & 3;
  const int lane = threadIdx.x;
  const int c = tile * 16 + (lane & 15);

  const float cs = ws_f[F_CNT + c];
  const float ct = ws_f[F_CNT + 64 + c];
  const float rs = 1.f / cs, rt = 1.f / ct, rst = 1.f / (cs + ct);

  bf16x8* out = (bf16x8*)(ws_f + BPACK);
#pragma unroll
  for (int s = 0; s < 8; ++s) {
    const int k0 = s * 32 + (lane >> 4) * 8;
    bf16x8 v;
#pragma unroll
    for (int j = 0; j < 8; ++j) {
      const float ss = ws_f[F_SUM_S + c * 256 + k0 + j];
      const float st = ws_f[F_SUM_T + c * 256 + k0 + j];
      float u;
      if (mat == 0) u = ss * rs;
      else if (mat == 1) u = st * rt;
      else u = (ss + st) * rst;
      v[j] = f2bf(u);
    }
    out[(bx * 8 + s) * 64 + lane] = v;
  }
}

// ---------------------------------------------------------------------------
// Kernel 4: MFMA logits + fused softmax/KL + reduce.
// 2048 blocks x 256 thr (__launch_bounds__(256,4) -> 128 VGPR budget).
// B staged in LDS mat-by-mat (32KB); inner loop = ds_read_b128 + MFMA.
// A: 16-load burst -> packed bf16 registers (single latency exposure).
// ---------------------------------------------------------------------------
__global__ __launch_bounds__(256, 4) void main_kernel(
    const float* __restrict__ src_feat, const float* __restrict__ trg_feat,
    const float* __restrict__ ws_f, double* __restrict__ acc) {
  __shared__ bf16x8 bsh[2048];  // 32 KB
  __shared__ float bsum[4];
  const int tid = threadIdx.x;
  const int wave = tid >> 6;
  const int lane = tid & 63;
  const int row0 = blockIdx.x * 64 + wave * 16;
  const float* base = (row0 < N_ROWS)
                          ? src_feat + (size_t)row0 * DIMS
                          : trg_feat + (size_t)(row0 - N_ROWS) * DIMS;
  const float* ap = base + (lane & 15) * DIMS + (lane >> 4) * 8;

  float4 lo[8], hi[8];
#pragma unroll
  for (int s = 0; s < 8; ++s) {
    lo[s] = *(const float4*)(ap + s * 32);
    hi[s] = *(const float4*)(ap + s * 32 + 4);
  }
  bf16x8 a[8];
#pragma unroll
  for (int s = 0; s < 8; ++s) a[s] = pack8(lo[s], hi[s]);

  const bf16x8* bp = (const bf16x8*)(ws_f + BPACK);
  f32x4 C[12];
#pragma unroll
  for (int m = 0; m < 12; ++m) C[m] = (f32x4){0.f, 0.f, 0.f, 0.f};

  for (int mat = 0; mat < 3; ++mat) {
    if (mat) __syncthreads();
#pragma unroll
    for (int j = 0; j < 8; ++j)
      bsh[tid + 256 * j] = bp[mat * 2048 + tid + 256 * j];
    __syncthreads();
#pragma unroll
    for (int s = 0; s < 8; ++s) {
#pragma unroll
      for (int t = 0; t < 4; ++t) {
        const bf16x8 bfr = bsh[(t * 8 + s) * 64 + lane];
        C[mat * 4 + t] =
            __builtin_amdgcn_mfma_f32_16x16x32_bf16(a[s], bfr, C[mat * 4 + t], 0, 0, 0);
      }
    }
  }

  // D mapping: row = (lane>>4)*4 + r, class = t*16 + (lane&15).
  float total = 0.f;
#pragma unroll
  for (int r = 0; r < 4; ++r) {
    float va[4], vb[4], vc[4];
#pragma unroll
    for (int t = 0; t < 4; ++t) {
      va[t] = C[t][r];
      vb[t] = C[4 + t][r];
      vc[t] = C[8 + t][r];
    }
    float ma = fmaxf(fmaxf(va[0], va[1]), fmaxf(va[2], va[3]));
    float mb = fmaxf(fmaxf(vb[0], vb[1]), fmaxf(vb[2], vb[3]));
    float mc = fmaxf(fmaxf(vc[0], vc[1]), fmaxf(vc[2], vc[3]));
    ma = seg_max16(ma); mb = seg_max16(mb); mc = seg_max16(mc);
    float ea[4], eb[4], ec[4];
    float sa = 0.f, sb = 0.f, sc = 0.f;
#pragma unroll
    for (int t = 0; t < 4; ++t) {
      ea[t] = __expf(va[t] - ma); sa += ea[t];
      eb[t] = __expf(vb[t] - mb); sb += eb[t];
      ec[t] = __expf(vc[t] - mc); sc += ec[t];
    }
    sa = seg_sum16(sa); sb = seg_sum16(sb); sc = seg_sum16(sc);
    const float La = ma + __logf(sa);
    const float Lb = mb + __logf(sb);
    const float Lc = mc + __logf(sc);
    const float isa = 1.f / sa, isb = 1.f / sb, isc = 1.f / sc;
#pragma unroll
    for (int t = 0; t < 4; ++t) {
      const float la = va[t] - La, lb = vb[t] - Lb, lc = vc[t] - Lc;
      const float pa = ea[t] * isa, pb = eb[t] * isb, pc = ec[t] * isc;
      total += pa * ((la - lb) + (la - lc)) + pb * ((lb - la) + (lb - lc)) +
               pc * ((lc - la) + (lc - lb));
    }
  }
  total = wave_sum64(total);
  if (lane == 0) bsum[wave] = total;
  __syncthreads();
  if (tid == 0) {
    const double t = (double)bsum[0] + bsum[1] + bsum[2] + bsum[3];
    atomicAdd(&acc[blockIdx.x & 63], t);
  }
}

// final = sum_of_6_kl_sums / (6 * 2N * C)
__global__ void finalize_kernel(const double* __restrict__ acc,
                                float* __restrict__ out) {
  double s = 0.0;
#pragma unroll
  for (int i = 0; i < 64; ++i) s += acc[i];
  out[0] = (float)(s / 50331648.0);  // 6 * 131072 * 64
}

extern "C" void kernel_launch(void* const* d_in, const int* in_sizes, int n_in,
                              void* d_out, int out_size, void* d_ws, size_t ws_size,
                              hipStream_t stream) {
  const float* src_feat = (const float*)d_in[0];
  const float* trg_feat = (const float*)d_in[1];
  const int* src_label = (const int*)d_in[2];
  const int* trg_label = (const int*)d_in[3];
  // d_in[4] (trg_feat_un) unused by the reference loss.
  float* ws_f = (float*)d_ws;
  double* acc = (double*)(ws_f + ACC_OFF);
  float* out = (float*)d_out;

  hipMemsetAsync((void*)acc, 0, 64 * sizeof(double), stream);

  seg_sum_kernel<<<1024, 256, 0, stream>>>(src_feat, trg_feat, src_label,
                                           trg_label, ws_f);
  reduce_kernel<<<257, 256, 0, stream>>>(ws_f);
  pack_kernel<<<12, 64, 0, stream>>>(ws_f);
  main_kernel<<<2048, 256, 0, stream>>>(src_feat, trg_feat, ws_f, acc);
  finalize_kernel<<<1, 1, 0, stream>>>(acc, out);
}